// Round 6
// baseline (4105.237 us; speedup 1.0000x reference)
//
#include <hip/hip_runtime.h>
#include <math.h>

// dims (hardcoded per reference)
#define T_STEPS 50
#define BB 8   // batch rows per block; grid = 2048/8 = 256 blocks = 1 per CU

// LDS pool offsets (floats)
#define O_XH    0        // xh_T[64][8]       (k-major, row minor; b128 broadcasts)
#define O_HT    512      // h_T[6][64][8]
#define O_HNT   3584     // hn_T[6][64][8]
#define O_HNR   6656     // hn_R[6][8][64]    (row-major mirror for C2)
#define O_K0    9728     // K0_R[8][64]
#define O_Q     10240    // Q_R[6][8][64]
#define O_QC    13312    // qc_R[6][8][128]
#define O_KC    19456    // kc_R[6][8][128]
#define O_VC    25600    // vc_R[6][8][64]
#define O_P0    28672    // p0_l[8][6]
#define O_ACT   28720    // act_l[8][6]
#define O_PART  13312    // G1 partials P[6][8][256] -- overlays qc+kc (dead in G1)
#define POOL_F  28768    // 115,072 bytes LDS

__device__ __forceinline__ void fma4(float4& a, const float4 v, const float s) {
  a.x = fmaf(v.x, s, a.x); a.y = fmaf(v.y, s, a.y);
  a.z = fmaf(v.z, s, a.z); a.w = fmaf(v.w, s, a.w);
}
__device__ __forceinline__ float4 mul4(const float4 a, const float4 b) {
  return make_float4(a.x * b.x, a.y * b.y, a.z * b.z, a.w * b.w);
}
__device__ __forceinline__ float sigmoidf_(float x) { return 1.0f / (1.0f + __expf(-x)); }
__device__ __forceinline__ float tanhf_(float x) {
  float ax = fabsf(x);
  float e = __expf(-2.0f * ax);
  float t = (1.0f - e) / (1.0f + e);
  return copysignf(t, x);
}

// Wcomb[r][k][g] = sum_v Wv[k][v] * Wih[r][v][g]  : [6][64][192] f32
__global__ void wcomb_kernel(const float* __restrict__ Wv, const float* __restrict__ Wih,
                             float* __restrict__ Wc) {
  int g = threadIdx.x;          // 0..191
  int f = blockIdx.x & 63;      // 0..63
  int r = blockIdx.x >> 6;      // 0..5
  float acc = 0.f;
#pragma unroll 8
  for (int v = 0; v < 128; ++v)
    acc = fmaf(Wv[f * 128 + v], Wih[(r * 128 + v) * 192 + g], acc);
  Wc[(r * 64 + f) * 192 + g] = acc;
}

__global__ __launch_bounds__(1024, 1) void rims_kernel(
    const float* __restrict__ x, const float* __restrict__ statics,
    const float* __restrict__ maskp, const float* __restrict__ delta,
    const float* __restrict__ xlast, const float* __restrict__ xmean,
    const float* __restrict__ wdgp, const float* __restrict__ bdgp,
    const float* __restrict__ Wk, const float* __restrict__ Wq,
    const float* __restrict__ Whh, const float* __restrict__ bih,
    const float* __restrict__ bhh, const float* __restrict__ Wqc,
    const float* __restrict__ Wkc, const float* __restrict__ Wvc,
    const float* __restrict__ W1, const float* __restrict__ b1,
    const float* __restrict__ W2, const float* __restrict__ b2,
    const float* __restrict__ Wcomb, float* __restrict__ out) {
  __shared__ float pool[POOL_F];

  const int tid = threadIdx.x;
  const int wave = tid >> 6;   // 0..15
  const int lane = tid & 63;
  const int b0 = blockIdx.x * BB;

  for (int i = tid; i < 3072; i += 1024) pool[O_HT + i] = 0.f;

  // X-phase constants (waves 0..7 own row = wave)
  const float wdg = wdgp[lane];
  const float bdg = bdgp[lane];
  const float xmv = xmean[(size_t)(b0 + (wave & 7)) * 64 + lane];
  // G1 biases (wave<12 owns rim r = wave>>1); r/z biases pre-combined
  float bR = 0.f, bZ = 0.f, bin = 0.f, bhn = 0.f;
  if (wave < 12) {
    const int r = wave >> 1;
    bR = bih[r * 192 + lane] + bhh[r * 192 + lane];
    bZ = bih[r * 192 + 64 + lane] + bhh[r * 192 + 64 + lane];
    bin = bih[r * 192 + 128 + lane];
    bhn = bhh[r * 192 + 128 + lane];
  }
  // X for t=0
  if (wave < 8) {
    size_t off = ((size_t)(b0 + wave) * T_STEPS + 0) * 64 + lane;
    float xt = x[off], mt = maskp[off], dt = delta[off], xl = xlast[off];
    float gm = __expf(-fmaxf(fmaf(dt, wdg, bdg), 0.f));
    pool[O_XH + lane * 8 + wave] = mt * xt + (1.f - mt) * (gm * xl + (1.f - gm) * xmv);
  }
  __syncthreads();

  for (int t = 0; t < T_STEPS; ++t) {
    // ---------------- G0: 7 units (proj p; all 8 rows). p0=K0, 1..6=Q[r]. No dup.
    if (wave < 7) {
      const int p = wave;
      const float* W = (p == 0) ? Wk : (Wq + (p - 1) * 4096);   // [k][col]
      const float* src = (p == 0) ? (pool + O_XH) : (pool + O_HT + (p - 1) * 512);
      float4 aL = {0, 0, 0, 0}, aH = {0, 0, 0, 0};
#pragma unroll 8
      for (int k = 0; k < 64; ++k) {
        float w = W[k * 64 + lane];                   // coalesced b32
        float4 s0 = *(const float4*)&src[k * 8];      // broadcast b128
        float4 s1 = *(const float4*)&src[k * 8 + 4];
        fma4(aL, s0, w); fma4(aH, s1, w);
      }
      float* dst = (p == 0) ? (pool + O_K0) : (pool + O_Q + (p - 1) * 512);
      dst[0 * 64 + lane] = aL.x; dst[1 * 64 + lane] = aL.y;
      dst[2 * 64 + lane] = aL.z; dst[3 * 64 + lane] = aL.w;
      dst[4 * 64 + lane] = aH.x; dst[5 * 64 + lane] = aH.y;
      dst[6 * 64 + lane] = aH.z; dst[7 * 64 + lane] = aH.w;
    }
    __syncthreads();
    // ---------------- R: logits, p0, top-4 mask (waves 0..7, row = wave)
    if (wave < 8) {
      const int row = wave;
      float k0 = pool[O_K0 + row * 64 + lane];
      float logit[6];
#pragma unroll
      for (int r = 0; r < 6; ++r) {
        float p = pool[O_Q + (r * 8 + row) * 64 + lane] * k0;
#pragma unroll
        for (int d = 1; d < 64; d <<= 1) p += __shfl_xor(p, d, 64);
        logit[r] = p * 0.125f;  // 1/sqrt(KS)
      }
      if (lane == 0) {
#pragma unroll
        for (int r = 0; r < 6; ++r) {
          int rank = 0;
#pragma unroll
          for (int r2 = 0; r2 < 6; ++r2)
            rank += (logit[r2] > logit[r]) || (logit[r2] == logit[r] && r2 < r);
          pool[O_P0 + row * 6 + r] = sigmoidf_(logit[r]);   // softmax([l,0])[0]
          pool[O_ACT + row * 6 + r] = (rank < 4) ? 1.f : 0.f;
        }
      }
    }
    __syncthreads();
    // ---------------- G1a: 12 units (rim, k-half), all 8 rows, no dup.
    // p0 folded into xh operand; r/z gates pre-summed (x+h), n kept split.
    float4 aR_L, aR_H, aZ_L, aZ_H, aUN_L, aUN_H, aGN_L, aGN_H;
    if (wave < 12) {
      const int r = wave >> 1, kh = wave & 1;
      const float* Wc = Wcomb + r * 12288 + kh * 32 * 192;   // [32][192]
      const float* Wh = Whh + r * 12288 + kh * 32 * 192;
      const float* xh = pool + O_XH + kh * 32 * 8;
      const float* hT = pool + O_HT + r * 512 + kh * 32 * 8;
      float4 p0L = make_float4(pool[O_P0 + 0 * 6 + r], pool[O_P0 + 1 * 6 + r],
                               pool[O_P0 + 2 * 6 + r], pool[O_P0 + 3 * 6 + r]);
      float4 p0H = make_float4(pool[O_P0 + 4 * 6 + r], pool[O_P0 + 5 * 6 + r],
                               pool[O_P0 + 6 * 6 + r], pool[O_P0 + 7 * 6 + r]);
      aR_L = aR_H = aZ_L = aZ_H = make_float4(0, 0, 0, 0);
      aUN_L = aUN_H = aGN_L = aGN_H = make_float4(0, 0, 0, 0);
#pragma unroll 4
      for (int k = 0; k < 32; ++k) {
        float w0 = Wc[k * 192 + lane], w1 = Wc[k * 192 + 64 + lane],
              w2 = Wc[k * 192 + 128 + lane];
        float v0 = Wh[k * 192 + lane], v1 = Wh[k * 192 + 64 + lane],
              v2 = Wh[k * 192 + 128 + lane];
        float4 x0 = *(const float4*)&xh[k * 8];
        float4 x1 = *(const float4*)&xh[k * 8 + 4];
        float4 h0 = *(const float4*)&hT[k * 8];
        float4 h1 = *(const float4*)&hT[k * 8 + 4];
        float4 xp0 = mul4(x0, p0L);
        float4 xp1 = mul4(x1, p0H);
        fma4(aR_L, xp0, w0); fma4(aR_L, h0, v0);
        fma4(aR_H, xp1, w0); fma4(aR_H, h1, v0);
        fma4(aZ_L, xp0, w1); fma4(aZ_L, h0, v1);
        fma4(aZ_H, xp1, w1); fma4(aZ_H, h1, v1);
        fma4(aUN_L, xp0, w2); fma4(aUN_H, xp1, w2);
        fma4(aGN_L, h0, v2); fma4(aGN_H, h1, v2);
      }
      // write partner's row-half partials to LDS (conflict-free: lane-consecutive)
      float* Pp = pool + O_PART + r * 8 * 256;
      const int orow = (kh == 0) ? 4 : 0;
      float4 wR = (kh == 0) ? aR_H : aR_L;
      float4 wZ = (kh == 0) ? aZ_H : aZ_L;
      float4 wU = (kh == 0) ? aUN_H : aUN_L;
      float4 wG = (kh == 0) ? aGN_H : aGN_L;
      Pp[(orow + 0) * 256 + lane] = wR.x; Pp[(orow + 1) * 256 + lane] = wR.y;
      Pp[(orow + 2) * 256 + lane] = wR.z; Pp[(orow + 3) * 256 + lane] = wR.w;
      Pp[(orow + 0) * 256 + 64 + lane] = wZ.x; Pp[(orow + 1) * 256 + 64 + lane] = wZ.y;
      Pp[(orow + 2) * 256 + 64 + lane] = wZ.z; Pp[(orow + 3) * 256 + 64 + lane] = wZ.w;
      Pp[(orow + 0) * 256 + 128 + lane] = wU.x; Pp[(orow + 1) * 256 + 128 + lane] = wU.y;
      Pp[(orow + 2) * 256 + 128 + lane] = wU.z; Pp[(orow + 3) * 256 + 128 + lane] = wU.w;
      Pp[(orow + 0) * 256 + 192 + lane] = wG.x; Pp[(orow + 1) * 256 + 192 + lane] = wG.y;
      Pp[(orow + 2) * 256 + 192 + lane] = wG.z; Pp[(orow + 3) * 256 + 192 + lane] = wG.w;
    }
    __syncthreads();
    // ---------------- G1b: combine partials + GRU pointwise (12 waves, 4 rows each)
    if (wave < 12) {
      const int r = wave >> 1, kh = wave & 1;
      const float* Pp = pool + O_PART + r * 8 * 256;
      const int crow = kh * 4;
      float oR[4], oZ[4], oU[4], oG[4];
      {
        float4 sR = (kh == 0) ? aR_L : aR_H;
        float4 sZ = (kh == 0) ? aZ_L : aZ_H;
        float4 sU = (kh == 0) ? aUN_L : aUN_H;
        float4 sG = (kh == 0) ? aGN_L : aGN_H;
        oR[0] = sR.x; oR[1] = sR.y; oR[2] = sR.z; oR[3] = sR.w;
        oZ[0] = sZ.x; oZ[1] = sZ.y; oZ[2] = sZ.z; oZ[3] = sZ.w;
        oU[0] = sU.x; oU[1] = sU.y; oU[2] = sU.z; oU[3] = sU.w;
        oG[0] = sG.x; oG[1] = sG.y; oG[2] = sG.z; oG[3] = sG.w;
      }
#pragma unroll
      for (int j = 0; j < 4; ++j) {
        const int row = crow + j;
        float cr = oR[j] + Pp[row * 256 + lane];
        float cz = oZ[j] + Pp[row * 256 + 64 + lane];
        float un = oU[j] + Pp[row * 256 + 128 + lane];
        float gn = oG[j] + Pp[row * 256 + 192 + lane];
        float rg = sigmoidf_(cr + bR);
        float zg = sigmoidf_(cz + bZ);
        float ng = tanhf_(un + bin + rg * (gn + bhn));
        float hold = pool[O_HT + (r * 64 + lane) * 8 + row];
        float hnv = (1.f - zg) * ng + zg * hold;
        pool[O_HNT + (r * 64 + lane) * 8 + row] = hnv;
        pool[O_HNR + (r * 8 + row) * 64 + lane] = hnv;
      }
    }
    __syncthreads();
    // ---------------- C1: 30 equal units (qc 12, kc 12, vc 6), all 8 rows, no dup
    for (int u = wave; u < 30; u += 16) {
      const float* W; float* dst; int wstride, r;
      if (u < 12) {
        r = u >> 1; const int ch = u & 1;
        W = Wqc + r * 8192 + ch * 64; wstride = 128;
        dst = pool + O_QC + r * 8 * 128 + ch * 64;
      } else if (u < 24) {
        const int v = u - 12; r = v >> 1; const int ch = v & 1;
        W = Wkc + r * 8192 + ch * 64; wstride = 128;
        dst = pool + O_KC + r * 8 * 128 + ch * 64;
      } else {
        r = u - 24;
        W = Wvc + r * 4096; wstride = 64;
        dst = pool + O_VC + r * 8 * 64;
      }
      const float* hn = pool + O_HNT + r * 512;
      float4 aL = {0, 0, 0, 0}, aH = {0, 0, 0, 0};
#pragma unroll 8
      for (int k = 0; k < 64; ++k) {
        float w = W[(size_t)k * wstride + lane];
        float4 h0 = *(const float4*)&hn[k * 8];
        float4 h1 = *(const float4*)&hn[k * 8 + 4];
        fma4(aL, h0, w); fma4(aH, h1, w);
      }
      const int ds = (u < 24) ? 128 : 64;
      dst[0 * ds + lane] = aL.x; dst[1 * ds + lane] = aL.y;
      dst[2 * ds + lane] = aL.z; dst[3 * ds + lane] = aL.w;
      dst[4 * ds + lane] = aH.x; dst[5 * ds + lane] = aH.y;
      dst[6 * ds + lane] = aH.z; dst[7 * ds + lane] = aH.w;
    }
    __syncthreads();
    // ---------------- C2: comm attention + state update (+ X for t+1 on waves 0..7)
    {
      float nx = 0.f, nm = 0.f, nd = 0.f, nxl = 0.f;
      if (wave < 8) {
        const int tn = (t + 1 < T_STEPS) ? (t + 1) : (T_STEPS - 1);
        size_t off = ((size_t)(b0 + wave) * T_STEPS + tn) * 64 + lane;
        nx = x[off]; nm = maskp[off]; nd = delta[off]; nxl = xlast[off];
      }
      const int row = wave >> 1;
      const int half = wave & 1;
      float kcA[6], kcB[6], vcv[6];
#pragma unroll
      for (int s = 0; s < 6; ++s) {
        kcA[s] = pool[O_KC + (s * 8 + row) * 128 + lane];
        kcB[s] = pool[O_KC + (s * 8 + row) * 128 + 64 + lane];
        vcv[s] = pool[O_VC + (s * 8 + row) * 64 + lane];
      }
      const int cOut = lane >> 4;            // output head for this lane's comm col
      const int srcLane = (cOut & 1) << 5;   // lane holding that head's reduced score
      const float inv_sq = 0.17677669529663687f;  // 1/sqrt(QC)
#pragma unroll
      for (int jr = 0; jr < 3; ++jr) {
        const int rr = half * 3 + jr;
        float qA = pool[O_QC + (rr * 8 + row) * 128 + lane];
        float qB = pool[O_QC + (rr * 8 + row) * 128 + 64 + lane];
        float sL[6], sH[6];
#pragma unroll
        for (int s = 0; s < 6; ++s) {
          float p = qA * kcA[s];
          p += __shfl_xor(p, 1, 64); p += __shfl_xor(p, 2, 64); p += __shfl_xor(p, 4, 64);
          p += __shfl_xor(p, 8, 64); p += __shfl_xor(p, 16, 64);
          sL[s] = p * inv_sq;   // head 0 (lanes 0-31) / head 1 (lanes 32-63)
          float q = qB * kcB[s];
          q += __shfl_xor(q, 1, 64); q += __shfl_xor(q, 2, 64); q += __shfl_xor(q, 4, 64);
          q += __shfl_xor(q, 8, 64); q += __shfl_xor(q, 16, 64);
          sH[s] = q * inv_sq;   // heads 2 / 3
        }
        float mL = sL[0], mH = sH[0];
#pragma unroll
        for (int s = 1; s < 6; ++s) { mL = fmaxf(mL, sL[s]); mH = fmaxf(mH, sH[s]); }
        float sumL = 0.f, sumH = 0.f;
#pragma unroll
        for (int s = 0; s < 6; ++s) {
          sL[s] = __expf(sL[s] - mL); sumL += sL[s];
          sH[s] = __expf(sH[s] - mH); sumH += sH[s];
        }
        float rLn = 1.f / sumL, rHn = 1.f / sumH;
        float comm = 0.f;
#pragma unroll
        for (int s = 0; s < 6; ++s) {
          float tL = __shfl(sL[s] * rLn, srcLane, 64);
          float tH = __shfl(sH[s] * rHn, srcLane, 64);
          float cp = (cOut < 2) ? tL : tH;
          comm = fmaf(cp, vcv[s], comm);
        }
        float mk = pool[O_ACT + row * 6 + rr];
        float hnv = pool[O_HNR + (rr * 8 + row) * 64 + lane];
        float hov = pool[O_HT + (rr * 64 + lane) * 8 + row];
        pool[O_HT + (rr * 64 + lane) * 8 + row] = (mk > 0.5f) ? (hnv + comm) : hov;
      }
      // GRU-D imputation for t+1 (xh_T unread until next G0)
      if (wave < 8) {
        float gm = __expf(-fmaxf(fmaf(nd, wdg, bdg), 0.f));
        pool[O_XH + lane * 8 + wave] = nm * nx + (1.f - nm) * (gm * nxl + (1.f - gm) * xmv);
      }
    }
    __syncthreads();
  }  // t

  // ---------------- final MLP head (waves 0..7, row = wave)
  if (wave < 8) {
    const int b = b0 + wave;
    float acc[10];
#pragma unroll
    for (int o = 0; o < 10; ++o) acc[o] = 0.f;
#pragma unroll
    for (int ii = 0; ii < 6; ++ii) {
      float f = pool[O_HT + (ii * 64 + lane) * 8 + wave];
      const float* w = W1 + (ii * 64 + lane) * 10;
#pragma unroll
      for (int o = 0; o < 10; ++o) acc[o] = fmaf(f, w[o], acc[o]);
    }
    if (lane < 16) {
      float f = statics[(size_t)b * 16 + lane];
      const float* w = W1 + (384 + lane) * 10;
#pragma unroll
      for (int o = 0; o < 10; ++o) acc[o] = fmaf(f, w[o], acc[o]);
    }
#pragma unroll
    for (int o = 0; o < 10; ++o) {
#pragma unroll
      for (int d = 1; d < 64; d <<= 1) acc[o] += __shfl_xor(acc[o], d, 64);
    }
    if (lane == 0) {
      float o0 = b2[0], o1 = b2[1];
#pragma unroll
      for (int o = 0; o < 10; ++o) {
        float a = fmaxf(acc[o] + b1[o], 0.f);
        o0 = fmaf(a, W2[o * 2 + 0], o0);
        o1 = fmaf(a, W2[o * 2 + 1], o1);
      }
      out[(size_t)b * 2 + 0] = o0;
      out[(size_t)b * 2 + 1] = o1;
    }
  }
}

extern "C" void kernel_launch(void* const* d_in, const int* in_sizes, int n_in,
                              void* d_out, int out_size, void* d_ws, size_t ws_size,
                              hipStream_t stream) {
  const float* x       = (const float*)d_in[0];
  const float* statics = (const float*)d_in[1];
  const float* maskp   = (const float*)d_in[2];
  const float* delta   = (const float*)d_in[3];
  const float* xlast   = (const float*)d_in[4];
  const float* xmean   = (const float*)d_in[5];
  const float* wdg     = (const float*)d_in[6];
  const float* bdg     = (const float*)d_in[7];
  const float* Wk      = (const float*)d_in[8];
  const float* Wv      = (const float*)d_in[9];
  const float* Wq      = (const float*)d_in[10];
  const float* Wih     = (const float*)d_in[11];
  const float* Whh     = (const float*)d_in[12];
  const float* bih     = (const float*)d_in[13];
  const float* bhh     = (const float*)d_in[14];
  const float* Wqc     = (const float*)d_in[15];
  const float* Wkc     = (const float*)d_in[16];
  const float* Wvc     = (const float*)d_in[17];
  const float* W1      = (const float*)d_in[18];
  const float* b1      = (const float*)d_in[19];
  const float* W2      = (const float*)d_in[20];
  const float* b2      = (const float*)d_in[21];
  float* Wcomb = (float*)d_ws;  // 6*64*192 floats = 294912 B

  wcomb_kernel<<<384, 192, 0, stream>>>(Wv, Wih, Wcomb);
  rims_kernel<<<256, 1024, 0, stream>>>(x, statics, maskp, delta, xlast, xmean,
                                        wdg, bdg, Wk, Wq, Whh, bih, bhh,
                                        Wqc, Wkc, Wvc, W1, b1, W2, b2,
                                        Wcomb, (float*)d_out);
}

// Round 7
// 2151.463 us; speedup vs baseline: 1.9081x; 1.9081x over previous
//
#include <hip/hip_runtime.h>
#include <math.h>

// dims (hardcoded per reference)
#define T_STEPS 50
#define BB 8   // batch rows per block; grid = 2048/8 = 256 blocks = 1 per CU

// LDS pool offsets (floats)
#define O_XH    0        // xh_T[64][8]       (k-major, row minor; b128 broadcasts)
#define O_HT    512      // h_T[6][64][8]
#define O_HNT   3584     // hn_T[6][64][8]
#define O_HNR   6656     // hn_R[6][8][64]    (row-major mirror for C2)
#define O_K0    9728     // K0_R[8][64]
#define O_Q     10240    // Q_R[6][8][64]
#define O_QC    13312    // qc_R[6][8][128]
#define O_KC    19456    // kc_R[6][8][128]
#define O_VC    25600    // vc_R[6][8][64]
#define O_P0    28672    // p0_l[8][6]
#define O_ACT   28720    // act_l[8][6]
// G1 partials PART[12 sides][3 gates][8 rows][64] -- overlays K0..vc (dead in G1)
#define O_PART  9728     // 18432 floats, ends 28160 <= 28672 (P0/ACT untouched)
#define POOL_F  28768    // 115,072 bytes LDS

__device__ __forceinline__ void fma4(float4& a, const float4 v, const float s) {
  a.x = fmaf(v.x, s, a.x); a.y = fmaf(v.y, s, a.y);
  a.z = fmaf(v.z, s, a.z); a.w = fmaf(v.w, s, a.w);
}
__device__ __forceinline__ float4 mul4(const float4 a, const float4 b) {
  return make_float4(a.x * b.x, a.y * b.y, a.z * b.z, a.w * b.w);
}
__device__ __forceinline__ float sigmoidf_(float x) { return 1.0f / (1.0f + __expf(-x)); }
__device__ __forceinline__ float tanhf_(float x) {
  float ax = fabsf(x);
  float e = __expf(-2.0f * ax);
  float t = (1.0f - e) / (1.0f + e);
  return copysignf(t, x);
}

// Wcomb[r][k][g] = sum_v Wv[k][v] * Wih[r][v][g]  : [6][64][192] f32
__global__ void wcomb_kernel(const float* __restrict__ Wv, const float* __restrict__ Wih,
                             float* __restrict__ Wc) {
  int g = threadIdx.x;          // 0..191
  int f = blockIdx.x & 63;      // 0..63
  int r = blockIdx.x >> 6;      // 0..5
  float acc = 0.f;
#pragma unroll 8
  for (int v = 0; v < 128; ++v)
    acc = fmaf(Wv[f * 128 + v], Wih[(r * 128 + v) * 192 + g], acc);
  Wc[(r * 64 + f) * 192 + g] = acc;
}

// waves_per_eu(4,4): pin VGPR budget to 128 (4 waves/EU = 16 waves/CU).
// R6 evidence: default budget for 1024-thread blocks is 64 VGPR -> scratch spill.
__global__ __launch_bounds__(1024, 1) __attribute__((amdgpu_waves_per_eu(4, 4)))
void rims_kernel(
    const float* __restrict__ x, const float* __restrict__ statics,
    const float* __restrict__ maskp, const float* __restrict__ delta,
    const float* __restrict__ xlast, const float* __restrict__ xmean,
    const float* __restrict__ wdgp, const float* __restrict__ bdgp,
    const float* __restrict__ Wk, const float* __restrict__ Wq,
    const float* __restrict__ Whh, const float* __restrict__ bih,
    const float* __restrict__ bhh, const float* __restrict__ Wqc,
    const float* __restrict__ Wkc, const float* __restrict__ Wvc,
    const float* __restrict__ W1, const float* __restrict__ b1,
    const float* __restrict__ W2, const float* __restrict__ b2,
    const float* __restrict__ Wcomb, float* __restrict__ out) {
  __shared__ float pool[POOL_F];

  const int tid = threadIdx.x;
  const int wave = tid >> 6;   // 0..15
  const int lane = tid & 63;
  const int b0 = blockIdx.x * BB;

  for (int i = tid; i < 3072; i += 1024) pool[O_HT + i] = 0.f;

  // X-phase constants (waves 0..7 own row = wave)
  const float wdg = wdgp[lane];
  const float bdg = bdgp[lane];
  const float xmv = xmean[(size_t)(b0 + (wave & 7)) * 64 + lane];
  // G1 biases (wave<12 owns rim r = wave>>1); r/z biases pre-combined
  float bR = 0.f, bZ = 0.f, bin = 0.f, bhn = 0.f;
  if (wave < 12) {
    const int r = wave >> 1;
    bR = bih[r * 192 + lane] + bhh[r * 192 + lane];
    bZ = bih[r * 192 + 64 + lane] + bhh[r * 192 + 64 + lane];
    bin = bih[r * 192 + 128 + lane];
    bhn = bhh[r * 192 + 128 + lane];
  }
  // X for t=0
  if (wave < 8) {
    size_t off = ((size_t)(b0 + wave) * T_STEPS + 0) * 64 + lane;
    float xt = x[off], mt = maskp[off], dt = delta[off], xl = xlast[off];
    float gm = __expf(-fmaxf(fmaf(dt, wdg, bdg), 0.f));
    pool[O_XH + lane * 8 + wave] = mt * xt + (1.f - mt) * (gm * xl + (1.f - gm) * xmv);
  }
  __syncthreads();

  for (int t = 0; t < T_STEPS; ++t) {
    // ---------------- G0: 7 units (proj p; all 8 rows). p0=K0, 1..6=Q[r]. No dup.
    if (wave < 7) {
      const int p = wave;
      const float* W = (p == 0) ? Wk : (Wq + (p - 1) * 4096);   // [k][col]
      const float* src = (p == 0) ? (pool + O_XH) : (pool + O_HT + (p - 1) * 512);
      float4 aL = {0, 0, 0, 0}, aH = {0, 0, 0, 0};
#pragma unroll 8
      for (int k = 0; k < 64; ++k) {
        float w = W[k * 64 + lane];                   // coalesced b32
        float4 s0 = *(const float4*)&src[k * 8];      // broadcast b128
        float4 s1 = *(const float4*)&src[k * 8 + 4];
        fma4(aL, s0, w); fma4(aH, s1, w);
      }
      float* dst = (p == 0) ? (pool + O_K0) : (pool + O_Q + (p - 1) * 512);
      dst[0 * 64 + lane] = aL.x; dst[1 * 64 + lane] = aL.y;
      dst[2 * 64 + lane] = aL.z; dst[3 * 64 + lane] = aL.w;
      dst[4 * 64 + lane] = aH.x; dst[5 * 64 + lane] = aH.y;
      dst[6 * 64 + lane] = aH.z; dst[7 * 64 + lane] = aH.w;
    }
    __syncthreads();
    // ---------------- R: logits, p0, top-4 mask (waves 0..7, row = wave)
    if (wave < 8) {
      const int row = wave;
      float k0 = pool[O_K0 + row * 64 + lane];
      float logit[6];
#pragma unroll
      for (int r = 0; r < 6; ++r) {
        float p = pool[O_Q + (r * 8 + row) * 64 + lane] * k0;
#pragma unroll
        for (int d = 1; d < 64; d <<= 1) p += __shfl_xor(p, d, 64);
        logit[r] = p * 0.125f;  // 1/sqrt(KS)
      }
      if (lane == 0) {
#pragma unroll
        for (int r = 0; r < 6; ++r) {
          int rank = 0;
#pragma unroll
          for (int r2 = 0; r2 < 6; ++r2)
            rank += (logit[r2] > logit[r]) || (logit[r2] == logit[r] && r2 < r);
          pool[O_P0 + row * 6 + r] = sigmoidf_(logit[r]);   // softmax([l,0])[0]
          pool[O_ACT + row * 6 + r] = (rank < 4) ? 1.f : 0.f;
        }
      }
    }
    __syncthreads();
    // ---------------- G1a: 12 units (rim, side). side0 = x-path (Wcomb, p0-scaled
    // after the k-loop), side1 = h-path (Whh). lane = h-col; 3 gates x 8 rows accs.
    // All partials -> LDS PART; NO registers live across the barrier.
    if (wave < 12) {
      const int r = wave >> 1, side = wave & 1;
      const float* W = ((side == 0) ? Wcomb : Whh) + r * 12288;   // [64][192]
      const float* src = (side == 0) ? (pool + O_XH) : (pool + O_HT + r * 512);
      float4 a0L = {0,0,0,0}, a0H = {0,0,0,0};
      float4 a1L = {0,0,0,0}, a1H = {0,0,0,0};
      float4 a2L = {0,0,0,0}, a2H = {0,0,0,0};
#pragma unroll 8
      for (int k = 0; k < 64; ++k) {
        float w0 = W[k * 192 + lane];
        float w1 = W[k * 192 + 64 + lane];
        float w2 = W[k * 192 + 128 + lane];
        float4 s0 = *(const float4*)&src[k * 8];
        float4 s1 = *(const float4*)&src[k * 8 + 4];
        fma4(a0L, s0, w0); fma4(a0H, s1, w0);
        fma4(a1L, s0, w1); fma4(a1H, s1, w1);
        fma4(a2L, s0, w2); fma4(a2H, s1, w2);
      }
      if (side == 0) {   // fold p0 per row: (p0*xh)@W == p0 (*) (xh@W)
        float4 p0L = make_float4(pool[O_P0 + 0 * 6 + r], pool[O_P0 + 1 * 6 + r],
                                 pool[O_P0 + 2 * 6 + r], pool[O_P0 + 3 * 6 + r]);
        float4 p0H = make_float4(pool[O_P0 + 4 * 6 + r], pool[O_P0 + 5 * 6 + r],
                                 pool[O_P0 + 6 * 6 + r], pool[O_P0 + 7 * 6 + r]);
        a0L = mul4(a0L, p0L); a0H = mul4(a0H, p0H);
        a1L = mul4(a1L, p0L); a1H = mul4(a1H, p0H);
        a2L = mul4(a2L, p0L); a2H = mul4(a2H, p0H);
      }
      // PART base for this (r,side): wave*1536; gate g at +g*512, [row*64+lane]
      float* Pb = pool + O_PART + wave * 1536;
      Pb[0 * 512 + 0 * 64 + lane] = a0L.x; Pb[0 * 512 + 1 * 64 + lane] = a0L.y;
      Pb[0 * 512 + 2 * 64 + lane] = a0L.z; Pb[0 * 512 + 3 * 64 + lane] = a0L.w;
      Pb[0 * 512 + 4 * 64 + lane] = a0H.x; Pb[0 * 512 + 5 * 64 + lane] = a0H.y;
      Pb[0 * 512 + 6 * 64 + lane] = a0H.z; Pb[0 * 512 + 7 * 64 + lane] = a0H.w;
      Pb[1 * 512 + 0 * 64 + lane] = a1L.x; Pb[1 * 512 + 1 * 64 + lane] = a1L.y;
      Pb[1 * 512 + 2 * 64 + lane] = a1L.z; Pb[1 * 512 + 3 * 64 + lane] = a1L.w;
      Pb[1 * 512 + 4 * 64 + lane] = a1H.x; Pb[1 * 512 + 5 * 64 + lane] = a1H.y;
      Pb[1 * 512 + 6 * 64 + lane] = a1H.z; Pb[1 * 512 + 7 * 64 + lane] = a1H.w;
      Pb[2 * 512 + 0 * 64 + lane] = a2L.x; Pb[2 * 512 + 1 * 64 + lane] = a2L.y;
      Pb[2 * 512 + 2 * 64 + lane] = a2L.z; Pb[2 * 512 + 3 * 64 + lane] = a2L.w;
      Pb[2 * 512 + 4 * 64 + lane] = a2H.x; Pb[2 * 512 + 5 * 64 + lane] = a2H.y;
      Pb[2 * 512 + 6 * 64 + lane] = a2H.z; Pb[2 * 512 + 7 * 64 + lane] = a2H.w;
    }
    __syncthreads();
    // ---------------- G1b: stateless GRU pointwise (12 units = (rim, row-half))
    if (wave < 12) {
      const int r = wave >> 1, rh = wave & 1;
      const float* Px = pool + O_PART + (r * 2 + 0) * 1536;
      const float* Ph = pool + O_PART + (r * 2 + 1) * 1536;
#pragma unroll
      for (int j = 0; j < 4; ++j) {
        const int row = rh * 4 + j;
        float xr = Px[row * 64 + lane];
        float xz = Px[512 + row * 64 + lane];
        float xn = Px[1024 + row * 64 + lane];
        float hr = Ph[row * 64 + lane];
        float hz = Ph[512 + row * 64 + lane];
        float hn_ = Ph[1024 + row * 64 + lane];
        float rg = sigmoidf_(xr + hr + bR);
        float zg = sigmoidf_(xz + hz + bZ);
        float ng = tanhf_(xn + bin + rg * (hn_ + bhn));
        float hold = pool[O_HT + (r * 64 + lane) * 8 + row];
        float hnv = (1.f - zg) * ng + zg * hold;
        pool[O_HNT + (r * 64 + lane) * 8 + row] = hnv;
        pool[O_HNR + (r * 8 + row) * 64 + lane] = hnv;
      }
    }
    __syncthreads();
    // ---------------- C1: 30 equal units (qc 12, kc 12, vc 6), all 8 rows, no dup
    for (int u = wave; u < 30; u += 16) {
      const float* W; float* dst; int wstride, r;
      if (u < 12) {
        r = u >> 1; const int ch = u & 1;
        W = Wqc + r * 8192 + ch * 64; wstride = 128;
        dst = pool + O_QC + r * 8 * 128 + ch * 64;
      } else if (u < 24) {
        const int v = u - 12; r = v >> 1; const int ch = v & 1;
        W = Wkc + r * 8192 + ch * 64; wstride = 128;
        dst = pool + O_KC + r * 8 * 128 + ch * 64;
      } else {
        r = u - 24;
        W = Wvc + r * 4096; wstride = 64;
        dst = pool + O_VC + r * 8 * 64;
      }
      const float* hn = pool + O_HNT + r * 512;
      float4 aL = {0, 0, 0, 0}, aH = {0, 0, 0, 0};
#pragma unroll 8
      for (int k = 0; k < 64; ++k) {
        float w = W[(size_t)k * wstride + lane];
        float4 h0 = *(const float4*)&hn[k * 8];
        float4 h1 = *(const float4*)&hn[k * 8 + 4];
        fma4(aL, h0, w); fma4(aH, h1, w);
      }
      const int ds = (u < 24) ? 128 : 64;
      dst[0 * ds + lane] = aL.x; dst[1 * ds + lane] = aL.y;
      dst[2 * ds + lane] = aL.z; dst[3 * ds + lane] = aL.w;
      dst[4 * ds + lane] = aH.x; dst[5 * ds + lane] = aH.y;
      dst[6 * ds + lane] = aH.z; dst[7 * ds + lane] = aH.w;
    }
    __syncthreads();
    // ---------------- C2: comm attention + state update (+ X for t+1 on waves 0..7)
    {
      float nx = 0.f, nm = 0.f, nd = 0.f, nxl = 0.f;
      if (wave < 8) {
        const int tn = (t + 1 < T_STEPS) ? (t + 1) : (T_STEPS - 1);
        size_t off = ((size_t)(b0 + wave) * T_STEPS + tn) * 64 + lane;
        nx = x[off]; nm = maskp[off]; nd = delta[off]; nxl = xlast[off];
      }
      const int row = wave >> 1;
      const int half = wave & 1;
      float kcA[6], kcB[6], vcv[6];
#pragma unroll
      for (int s = 0; s < 6; ++s) {
        kcA[s] = pool[O_KC + (s * 8 + row) * 128 + lane];
        kcB[s] = pool[O_KC + (s * 8 + row) * 128 + 64 + lane];
        vcv[s] = pool[O_VC + (s * 8 + row) * 64 + lane];
      }
      const int cOut = lane >> 4;            // output head for this lane's comm col
      const int srcLane = (cOut & 1) << 5;   // lane holding that head's reduced score
      const float inv_sq = 0.17677669529663687f;  // 1/sqrt(QC)
#pragma unroll
      for (int jr = 0; jr < 3; ++jr) {
        const int rr = half * 3 + jr;
        float qA = pool[O_QC + (rr * 8 + row) * 128 + lane];
        float qB = pool[O_QC + (rr * 8 + row) * 128 + 64 + lane];
        float sL[6], sH[6];
#pragma unroll
        for (int s = 0; s < 6; ++s) {
          float p = qA * kcA[s];
          p += __shfl_xor(p, 1, 64); p += __shfl_xor(p, 2, 64); p += __shfl_xor(p, 4, 64);
          p += __shfl_xor(p, 8, 64); p += __shfl_xor(p, 16, 64);
          sL[s] = p * inv_sq;   // head 0 (lanes 0-31) / head 1 (lanes 32-63)
          float q = qB * kcB[s];
          q += __shfl_xor(q, 1, 64); q += __shfl_xor(q, 2, 64); q += __shfl_xor(q, 4, 64);
          q += __shfl_xor(q, 8, 64); q += __shfl_xor(q, 16, 64);
          sH[s] = q * inv_sq;   // heads 2 / 3
        }
        float mL = sL[0], mH = sH[0];
#pragma unroll
        for (int s = 1; s < 6; ++s) { mL = fmaxf(mL, sL[s]); mH = fmaxf(mH, sH[s]); }
        float sumL = 0.f, sumH = 0.f;
#pragma unroll
        for (int s = 0; s < 6; ++s) {
          sL[s] = __expf(sL[s] - mL); sumL += sL[s];
          sH[s] = __expf(sH[s] - mH); sumH += sH[s];
        }
        float rLn = 1.f / sumL, rHn = 1.f / sumH;
        float comm = 0.f;
#pragma unroll
        for (int s = 0; s < 6; ++s) {
          float tL = __shfl(sL[s] * rLn, srcLane, 64);
          float tH = __shfl(sH[s] * rHn, srcLane, 64);
          float cp = (cOut < 2) ? tL : tH;
          comm = fmaf(cp, vcv[s], comm);
        }
        float mk = pool[O_ACT + row * 6 + rr];
        float hnv = pool[O_HNR + (rr * 8 + row) * 64 + lane];
        float hov = pool[O_HT + (rr * 64 + lane) * 8 + row];
        pool[O_HT + (rr * 64 + lane) * 8 + row] = (mk > 0.5f) ? (hnv + comm) : hov;
      }
      // GRU-D imputation for t+1 (xh_T unread until next G0)
      if (wave < 8) {
        float gm = __expf(-fmaxf(fmaf(nd, wdg, bdg), 0.f));
        pool[O_XH + lane * 8 + wave] = nm * nx + (1.f - nm) * (gm * nxl + (1.f - gm) * xmv);
      }
    }
    __syncthreads();
  }  // t

  // ---------------- final MLP head (waves 0..7, row = wave)
  if (wave < 8) {
    const int b = b0 + wave;
    float acc[10];
#pragma unroll
    for (int o = 0; o < 10; ++o) acc[o] = 0.f;
#pragma unroll
    for (int ii = 0; ii < 6; ++ii) {
      float f = pool[O_HT + (ii * 64 + lane) * 8 + wave];
      const float* w = W1 + (ii * 64 + lane) * 10;
#pragma unroll
      for (int o = 0; o < 10; ++o) acc[o] = fmaf(f, w[o], acc[o]);
    }
    if (lane < 16) {
      float f = statics[(size_t)b * 16 + lane];
      const float* w = W1 + (384 + lane) * 10;
#pragma unroll
      for (int o = 0; o < 10; ++o) acc[o] = fmaf(f, w[o], acc[o]);
    }
#pragma unroll
    for (int o = 0; o < 10; ++o) {
#pragma unroll
      for (int d = 1; d < 64; d <<= 1) acc[o] += __shfl_xor(acc[o], d, 64);
    }
    if (lane == 0) {
      float o0 = b2[0], o1 = b2[1];
#pragma unroll
      for (int o = 0; o < 10; ++o) {
        float a = fmaxf(acc[o] + b1[o], 0.f);
        o0 = fmaf(a, W2[o * 2 + 0], o0);
        o1 = fmaf(a, W2[o * 2 + 1], o1);
      }
      out[(size_t)b * 2 + 0] = o0;
      out[(size_t)b * 2 + 1] = o1;
    }
  }
}

extern "C" void kernel_launch(void* const* d_in, const int* in_sizes, int n_in,
                              void* d_out, int out_size, void* d_ws, size_t ws_size,
                              hipStream_t stream) {
  const float* x       = (const float*)d_in[0];
  const float* statics = (const float*)d_in[1];
  const float* maskp   = (const float*)d_in[2];
  const float* delta   = (const float*)d_in[3];
  const float* xlast   = (const float*)d_in[4];
  const float* xmean   = (const float*)d_in[5];
  const float* wdg     = (const float*)d_in[6];
  const float* bdg     = (const float*)d_in[7];
  const float* Wk      = (const float*)d_in[8];
  const float* Wv      = (const float*)d_in[9];
  const float* Wq      = (const float*)d_in[10];
  const float* Wih     = (const float*)d_in[11];
  const float* Whh     = (const float*)d_in[12];
  const float* bih     = (const float*)d_in[13];
  const float* bhh     = (const float*)d_in[14];
  const float* Wqc     = (const float*)d_in[15];
  const float* Wkc     = (const float*)d_in[16];
  const float* Wvc     = (const float*)d_in[17];
  const float* W1      = (const float*)d_in[18];
  const float* b1      = (const float*)d_in[19];
  const float* W2      = (const float*)d_in[20];
  const float* b2      = (const float*)d_in[21];
  float* Wcomb = (float*)d_ws;  // 6*64*192 floats = 294912 B

  wcomb_kernel<<<384, 192, 0, stream>>>(Wv, Wih, Wcomb);
  rims_kernel<<<256, 1024, 0, stream>>>(x, statics, maskp, delta, xlast, xmean,
                                        wdg, bdg, Wk, Wq, Whh, bih, bhh,
                                        Wqc, Wkc, Wvc, W1, b1, W2, b2,
                                        Wcomb, (float*)d_out);
}

// Round 8
// 2132.696 us; speedup vs baseline: 1.9249x; 1.0088x over previous
//
#include <hip/hip_runtime.h>
#include <math.h>

// dims (hardcoded per reference)
#define T_STEPS 50
#define BB 8   // batch rows per block; grid = 2048/8 = 256 blocks = 1 per CU

// LDS pool offsets (floats)
#define O_XH    0        // xh_T[64][8]   (k-major, row minor; b128 broadcast reads)
#define O_HT    512      // h_T[6][64][8]
#define O_HNT   3584     // hn_T[6][64][8]
#define O_K0    6656     // K0_R[8][64]   (row-major; survives A->D)
#define O_Q     7168     // Q_R[6][8][64] (row-major; survives A->D)
#define O_QC    10240    // qc_R[6][8][128]
#define O_KC    16384    // kc_R[6][8][128]
#define O_VC    22528    // vc_R[6][8][64]   (ends 25600)
#define O_PART  10240    // G1 partials [12 units][3 gates][8 rows][64] = 18432 floats
                         // overlays QC/KC/VC (+spare): PART live A->B, QC/KC/VC live C->D
#define POOL_F  28672    // 114,688 B LDS

__device__ __forceinline__ void fma4(float4& a, const float4 v, const float s) {
  a.x = fmaf(v.x, s, a.x); a.y = fmaf(v.y, s, a.y);
  a.z = fmaf(v.z, s, a.z); a.w = fmaf(v.w, s, a.w);
}
__device__ __forceinline__ float sigmoidf_(float x) { return 1.0f / (1.0f + __expf(-x)); }
__device__ __forceinline__ float tanhf_(float x) {
  float ax = fabsf(x);
  float e = __expf(-2.0f * ax);
  float t = (1.0f - e) / (1.0f + e);
  return copysignf(t, x);
}

// Wcomb[r][k][g] = sum_v Wv[k][v] * Wih[r][v][g]  : [6][64][192] f32
__global__ void wcomb_kernel(const float* __restrict__ Wv, const float* __restrict__ Wih,
                             float* __restrict__ Wc) {
  int g = threadIdx.x;          // 0..191
  int f = blockIdx.x & 63;      // 0..63
  int r = blockIdx.x >> 6;      // 0..5
  float acc = 0.f;
#pragma unroll 8
  for (int v = 0; v < 128; ++v)
    acc = fmaf(Wv[f * 128 + v], Wih[(r * 128 + v) * 192 + g], acc);
  Wc[(r * 64 + f) * 192 + g] = acc;
}

// waves_per_eu(4,4): 128-VGPR budget for the 16-wave block (R6: default=64 -> spill).
__global__ __launch_bounds__(1024, 1) __attribute__((amdgpu_waves_per_eu(4, 4)))
void rims_kernel(
    const float* __restrict__ x, const float* __restrict__ statics,
    const float* __restrict__ maskp, const float* __restrict__ delta,
    const float* __restrict__ xlast, const float* __restrict__ xmean,
    const float* __restrict__ wdgp, const float* __restrict__ bdgp,
    const float* __restrict__ Wk, const float* __restrict__ Wq,
    const float* __restrict__ Whh, const float* __restrict__ bih,
    const float* __restrict__ bhh, const float* __restrict__ Wqc,
    const float* __restrict__ Wkc, const float* __restrict__ Wvc,
    const float* __restrict__ W1, const float* __restrict__ b1,
    const float* __restrict__ W2, const float* __restrict__ b2,
    const float* __restrict__ Wcomb, float* __restrict__ out) {
  __shared__ float pool[POOL_F];

  const int tid = threadIdx.x;
  const int wave = tid >> 6;   // 0..15
  const int lane = tid & 63;
  const int b0 = blockIdx.x * BB;

  for (int i = tid; i < 3072; i += 1024) pool[O_HT + i] = 0.f;

  // X-phase constants (waves 0..7 own X-row = wave)
  const float wdg = wdgp[lane];
  const float bdg = bdgp[lane];
  const float xmv = xmean[(size_t)(b0 + (wave & 7)) * 64 + lane];
  // G1 biases (waves 0..11 own rim r = wave>>1); r/z biases pre-combined
  float bR = 0.f, bZ = 0.f, bin = 0.f, bhn = 0.f;
  if (wave < 12) {
    const int r = wave >> 1;
    bR = bih[r * 192 + lane] + bhh[r * 192 + lane];
    bZ = bih[r * 192 + 64 + lane] + bhh[r * 192 + 64 + lane];
    bin = bih[r * 192 + 128 + lane];
    bhn = bhh[r * 192 + 128 + lane];
  }
  // X for t=0
  if (wave < 8) {
    size_t off = ((size_t)(b0 + wave) * T_STEPS + 0) * 64 + lane;
    float xt = x[off], mt = maskp[off], dt = delta[off], xl = xlast[off];
    float gm = __expf(-fmaxf(fmaf(dt, wdg, bdg), 0.f));
    pool[O_XH + lane * 8 + wave] = mt * xt + (1.f - mt) * (gm * xl + (1.f - gm) * xmv);
  }
  __syncthreads();

  for (int t = 0; t < T_STEPS; ++t) {
    // ===== Phase A: G1a (12 units: rim x side, raw partials) + G0 (7 units on 4 waves)
    if (wave < 12) {
      const int r = wave >> 1, side = wave & 1;
      const float* W = ((side == 0) ? Wcomb : Whh) + r * 12288;   // [64][192]
      const float* src = (side == 0) ? (pool + O_XH) : (pool + O_HT + r * 512);
      float4 a0L = {0,0,0,0}, a0H = {0,0,0,0};
      float4 a1L = {0,0,0,0}, a1H = {0,0,0,0};
      float4 a2L = {0,0,0,0}, a2H = {0,0,0,0};
#pragma unroll 8
      for (int k = 0; k < 64; ++k) {
        float w0 = W[k * 192 + lane];
        float w1 = W[k * 192 + 64 + lane];
        float w2 = W[k * 192 + 128 + lane];
        float4 s0 = *(const float4*)&src[k * 8];
        float4 s1 = *(const float4*)&src[k * 8 + 4];
        fma4(a0L, s0, w0); fma4(a0H, s1, w0);
        fma4(a1L, s0, w1); fma4(a1H, s1, w1);
        fma4(a2L, s0, w2); fma4(a2H, s1, w2);
      }
      float* Pb = pool + O_PART + wave * 1536;
      Pb[0 * 512 + 0 * 64 + lane] = a0L.x; Pb[0 * 512 + 1 * 64 + lane] = a0L.y;
      Pb[0 * 512 + 2 * 64 + lane] = a0L.z; Pb[0 * 512 + 3 * 64 + lane] = a0L.w;
      Pb[0 * 512 + 4 * 64 + lane] = a0H.x; Pb[0 * 512 + 5 * 64 + lane] = a0H.y;
      Pb[0 * 512 + 6 * 64 + lane] = a0H.z; Pb[0 * 512 + 7 * 64 + lane] = a0H.w;
      Pb[1 * 512 + 0 * 64 + lane] = a1L.x; Pb[1 * 512 + 1 * 64 + lane] = a1L.y;
      Pb[1 * 512 + 2 * 64 + lane] = a1L.z; Pb[1 * 512 + 3 * 64 + lane] = a1L.w;
      Pb[1 * 512 + 4 * 64 + lane] = a1H.x; Pb[1 * 512 + 5 * 64 + lane] = a1H.y;
      Pb[1 * 512 + 6 * 64 + lane] = a1H.z; Pb[1 * 512 + 7 * 64 + lane] = a1H.w;
      Pb[2 * 512 + 0 * 64 + lane] = a2L.x; Pb[2 * 512 + 1 * 64 + lane] = a2L.y;
      Pb[2 * 512 + 2 * 64 + lane] = a2L.z; Pb[2 * 512 + 3 * 64 + lane] = a2L.w;
      Pb[2 * 512 + 4 * 64 + lane] = a2H.x; Pb[2 * 512 + 5 * 64 + lane] = a2H.y;
      Pb[2 * 512 + 6 * 64 + lane] = a2H.z; Pb[2 * 512 + 7 * 64 + lane] = a2H.w;
    } else {
      // G0 units: wave12 -> p{0,1}, 13 -> {2,3}, 14 -> {4,5}, 15 -> {6}
      const int p0i = (wave - 12) * 2;
      for (int p = p0i; p < p0i + 2 && p < 7; ++p) {
        const float* W = (p == 0) ? Wk : (Wq + (p - 1) * 4096);   // [k][col]
        const float* src = (p == 0) ? (pool + O_XH) : (pool + O_HT + (p - 1) * 512);
        float4 aL = {0, 0, 0, 0}, aH = {0, 0, 0, 0};
#pragma unroll 8
        for (int k = 0; k < 64; ++k) {
          float w = W[k * 64 + lane];
          float4 s0 = *(const float4*)&src[k * 8];
          float4 s1 = *(const float4*)&src[k * 8 + 4];
          fma4(aL, s0, w); fma4(aH, s1, w);
        }
        float* dst = (p == 0) ? (pool + O_K0) : (pool + O_Q + (p - 1) * 512);
        dst[0 * 64 + lane] = aL.x; dst[1 * 64 + lane] = aL.y;
        dst[2 * 64 + lane] = aL.z; dst[3 * 64 + lane] = aL.w;
        dst[4 * 64 + lane] = aH.x; dst[5 * 64 + lane] = aH.y;
        dst[6 * 64 + lane] = aH.z; dst[7 * 64 + lane] = aH.w;
      }
    }
    __syncthreads();
    // ===== Phase B: G1b — own p0 (4 dots, no redundancy), combine, GRU -> hn
    if (wave < 12) {
      const int r = wave >> 1, rh = wave & 1;
      const float* Px = pool + O_PART + (2 * r) * 1536;
      const float* Ph = pool + O_PART + (2 * r + 1) * 1536;
      // 4 routing dots with ILP
      float dd[4];
#pragma unroll
      for (int j = 0; j < 4; ++j) {
        const int row = rh * 4 + j;
        dd[j] = pool[O_Q + (r * 8 + row) * 64 + lane] * pool[O_K0 + row * 64 + lane];
      }
#pragma unroll
      for (int d = 1; d < 64; d <<= 1) {
#pragma unroll
        for (int j = 0; j < 4; ++j) dd[j] += __shfl_xor(dd[j], d, 64);
      }
#pragma unroll
      for (int j = 0; j < 4; ++j) {
        const int row = rh * 4 + j;
        float p0 = sigmoidf_(dd[j] * 0.125f);   // softmax([logit,0])[0]
        float xr = Px[row * 64 + lane];
        float xz = Px[512 + row * 64 + lane];
        float xn = Px[1024 + row * 64 + lane];
        float hr = Ph[row * 64 + lane];
        float hz = Ph[512 + row * 64 + lane];
        float hn_ = Ph[1024 + row * 64 + lane];
        float rg = sigmoidf_(fmaf(p0, xr, hr) + bR);
        float zg = sigmoidf_(fmaf(p0, xz, hz) + bZ);
        float ng = tanhf_(fmaf(p0, xn, bin) + rg * (hn_ + bhn));
        float hold = pool[O_HT + (r * 64 + lane) * 8 + row];
        pool[O_HNT + (r * 64 + lane) * 8 + row] = (1.f - zg) * ng + zg * hold;
      }
    }
    __syncthreads();
    // ===== Phase C: C1 — 30 no-dup units (qc 12, kc 12, vc 6)
    for (int u = wave; u < 30; u += 16) {
      const float* W; float* dst; int wstride, r;
      if (u < 12) {
        r = u >> 1; const int ch = u & 1;
        W = Wqc + r * 8192 + ch * 64; wstride = 128;
        dst = pool + O_QC + r * 8 * 128 + ch * 64;
      } else if (u < 24) {
        const int v = u - 12; r = v >> 1; const int ch = v & 1;
        W = Wkc + r * 8192 + ch * 64; wstride = 128;
        dst = pool + O_KC + r * 8 * 128 + ch * 64;
      } else {
        r = u - 24;
        W = Wvc + r * 4096; wstride = 64;
        dst = pool + O_VC + r * 8 * 64;
      }
      const float* hn = pool + O_HNT + r * 512;
      float4 aL = {0, 0, 0, 0}, aH = {0, 0, 0, 0};
#pragma unroll 8
      for (int k = 0; k < 64; ++k) {
        float w = W[(size_t)k * wstride + lane];
        float4 h0 = *(const float4*)&hn[k * 8];
        float4 h1 = *(const float4*)&hn[k * 8 + 4];
        fma4(aL, h0, w); fma4(aH, h1, w);
      }
      const int ds = (u < 24) ? 128 : 64;
      dst[0 * ds + lane] = aL.x; dst[1 * ds + lane] = aL.y;
      dst[2 * ds + lane] = aL.z; dst[3 * ds + lane] = aL.w;
      dst[4 * ds + lane] = aH.x; dst[5 * ds + lane] = aH.y;
      dst[6 * ds + lane] = aH.z; dst[7 * ds + lane] = aH.w;
    }
    __syncthreads();
    // ===== Phase D: C2 (+ in-wave act recompute) + X(t+1)
    {
      float nx = 0.f, nm = 0.f, nd = 0.f, nxl = 0.f;
      if (wave < 8) {   // issue next-step input loads early; latency hides under C2
        const int tn = (t + 1 < T_STEPS) ? (t + 1) : (T_STEPS - 1);
        size_t off = ((size_t)(b0 + wave) * T_STEPS + tn) * 64 + lane;
        nx = x[off]; nm = maskp[off]; nd = delta[off]; nxl = xlast[off];
      }
      const int row = wave >> 1;
      const int half = wave & 1;
      // act: all 6 routing logits for this row (butterfly leaves result in all lanes)
      float lg[6];
      {
        float k0v = pool[O_K0 + row * 64 + lane];
#pragma unroll
        for (int r = 0; r < 6; ++r)
          lg[r] = pool[O_Q + (r * 8 + row) * 64 + lane] * k0v;
#pragma unroll
        for (int d = 1; d < 64; d <<= 1) {
#pragma unroll
          for (int r = 0; r < 6; ++r) lg[r] += __shfl_xor(lg[r], d, 64);
        }
      }
      float kcA[6], kcB[6], vcv[6];
#pragma unroll
      for (int s = 0; s < 6; ++s) {
        kcA[s] = pool[O_KC + (s * 8 + row) * 128 + lane];
        kcB[s] = pool[O_KC + (s * 8 + row) * 128 + 64 + lane];
        vcv[s] = pool[O_VC + (s * 8 + row) * 64 + lane];
      }
      const int cOut = lane >> 4;
      const int srcLane = (cOut & 1) << 5;
      const float inv_sq = 0.17677669529663687f;  // 1/sqrt(QC)
#pragma unroll
      for (int jr = 0; jr < 3; ++jr) {
        const int rr = half * 3 + jr;
        // stable top-4 on logits (== top_k(-null_prob)): rank via exact compares
        int rank = 0;
#pragma unroll
        for (int r2 = 0; r2 < 6; ++r2)
          rank += (lg[r2] > lg[rr]) || (lg[r2] == lg[rr] && r2 < rr);
        const bool active = (rank < 4);
        float qA = pool[O_QC + (rr * 8 + row) * 128 + lane];
        float qB = pool[O_QC + (rr * 8 + row) * 128 + 64 + lane];
        float sL[6], sH[6];
#pragma unroll
        for (int s = 0; s < 6; ++s) {
          float p = qA * kcA[s];
          p += __shfl_xor(p, 1, 64); p += __shfl_xor(p, 2, 64); p += __shfl_xor(p, 4, 64);
          p += __shfl_xor(p, 8, 64); p += __shfl_xor(p, 16, 64);
          sL[s] = p * inv_sq;   // heads 0/1 (lane<32 / lane>=32)
          float q = qB * kcB[s];
          q += __shfl_xor(q, 1, 64); q += __shfl_xor(q, 2, 64); q += __shfl_xor(q, 4, 64);
          q += __shfl_xor(q, 8, 64); q += __shfl_xor(q, 16, 64);
          sH[s] = q * inv_sq;   // heads 2/3
        }
        float mL = sL[0], mH = sH[0];
#pragma unroll
        for (int s = 1; s < 6; ++s) { mL = fmaxf(mL, sL[s]); mH = fmaxf(mH, sH[s]); }
        float sumL = 0.f, sumH = 0.f;
#pragma unroll
        for (int s = 0; s < 6; ++s) {
          sL[s] = __expf(sL[s] - mL); sumL += sL[s];
          sH[s] = __expf(sH[s] - mH); sumH += sH[s];
        }
        float rLn = 1.f / sumL, rHn = 1.f / sumH;
        float comm = 0.f;
#pragma unroll
        for (int s = 0; s < 6; ++s) {
          float tL = __shfl(sL[s] * rLn, srcLane, 64);
          float tH = __shfl(sH[s] * rHn, srcLane, 64);
          float cp = (cOut < 2) ? tL : tH;
          comm = fmaf(cp, vcv[s], comm);
        }
        float hnv = pool[O_HNT + (rr * 64 + lane) * 8 + row];
        float hov = pool[O_HT + (rr * 64 + lane) * 8 + row];
        pool[O_HT + (rr * 64 + lane) * 8 + row] = active ? (hnv + comm) : hov;
      }
      // GRU-D imputation for t+1 (XH unread until next phase A)
      if (wave < 8) {
        float gm = __expf(-fmaxf(fmaf(nd, wdg, bdg), 0.f));
        pool[O_XH + lane * 8 + wave] = nm * nx + (1.f - nm) * (gm * nxl + (1.f - gm) * xmv);
      }
    }
    __syncthreads();
  }  // t

  // ---------------- final MLP head (waves 0..7, row = wave)
  if (wave < 8) {
    const int b = b0 + wave;
    float acc[10];
#pragma unroll
    for (int o = 0; o < 10; ++o) acc[o] = 0.f;
#pragma unroll
    for (int ii = 0; ii < 6; ++ii) {
      float f = pool[O_HT + (ii * 64 + lane) * 8 + wave];
      const float* w = W1 + (ii * 64 + lane) * 10;
#pragma unroll
      for (int o = 0; o < 10; ++o) acc[o] = fmaf(f, w[o], acc[o]);
    }
    if (lane < 16) {
      float f = statics[(size_t)b * 16 + lane];
      const float* w = W1 + (384 + lane) * 10;
#pragma unroll
      for (int o = 0; o < 10; ++o) acc[o] = fmaf(f, w[o], acc[o]);
    }
#pragma unroll
    for (int o = 0; o < 10; ++o) {
#pragma unroll
      for (int d = 1; d < 64; d <<= 1) acc[o] += __shfl_xor(acc[o], d, 64);
    }
    if (lane == 0) {
      float o0 = b2[0], o1 = b2[1];
#pragma unroll
      for (int o = 0; o < 10; ++o) {
        float a = fmaxf(acc[o] + b1[o], 0.f);
        o0 = fmaf(a, W2[o * 2 + 0], o0);
        o1 = fmaf(a, W2[o * 2 + 1], o1);
      }
      out[(size_t)b * 2 + 0] = o0;
      out[(size_t)b * 2 + 1] = o1;
    }
  }
}

extern "C" void kernel_launch(void* const* d_in, const int* in_sizes, int n_in,
                              void* d_out, int out_size, void* d_ws, size_t ws_size,
                              hipStream_t stream) {
  const float* x       = (const float*)d_in[0];
  const float* statics = (const float*)d_in[1];
  const float* maskp   = (const float*)d_in[2];
  const float* delta   = (const float*)d_in[3];
  const float* xlast   = (const float*)d_in[4];
  const float* xmean   = (const float*)d_in[5];
  const float* wdg     = (const float*)d_in[6];
  const float* bdg     = (const float*)d_in[7];
  const float* Wk      = (const float*)d_in[8];
  const float* Wv      = (const float*)d_in[9];
  const float* Wq      = (const float*)d_in[10];
  const float* Wih     = (const float*)d_in[11];
  const float* Whh     = (const float*)d_in[12];
  const float* bih     = (const float*)d_in[13];
  const float* bhh     = (const float*)d_in[14];
  const float* Wqc     = (const float*)d_in[15];
  const float* Wkc     = (const float*)d_in[16];
  const float* Wvc     = (const float*)d_in[17];
  const float* W1      = (const float*)d_in[18];
  const float* b1      = (const float*)d_in[19];
  const float* W2      = (const float*)d_in[20];
  const float* b2      = (const float*)d_in[21];
  float* Wcomb = (float*)d_ws;  // 6*64*192 floats = 294912 B

  wcomb_kernel<<<384, 192, 0, stream>>>(Wv, Wih, Wcomb);
  rims_kernel<<<256, 1024, 0, stream>>>(x, statics, maskp, delta, xlast, xmean,
                                        wdg, bdg, Wk, Wq, Whh, bih, bhh,
                                        Wqc, Wkc, Wvc, W1, b1, W2, b2,
                                        Wcomb, (float*)d_out);
}